// Round 3
// baseline (26.122 us; speedup 1.0000x reference)
//
#include <hip/hip_runtime.h>

// E8 attention, closed-form softmax over the E8 root codebook.
//
// Per (token, head), q in R^8, s_r = (q.r)/sqrt(8), p = softmax(s),
// ctx = sum_r p_r r. With c = 1/(2 sqrt 8), w_k = exp(c q_k), iw = 1/w:
//   a_k = w + iw, b_k = w - iw, alpha_k = a_k^2 - 2, beta_k = a_k b_k.
// Pair roots (112): numer_i = beta_i (Sa - alpha_i),
//   denom_pair = 0.5 (Sa^2 - sum alpha^2).
// Half roots (128, even parity): denom_half = 0.5 (prod a + prod b),
//   numer_k = 0.25 (b_k prod_{m!=k} a_m + a_k prod_{m!=k} b_m).
// Exact reformulation; |scores| ~ 1 so f32 exp cannot overflow.
//
// Lane layout (latency attack): each (token, head) is split across 2 lanes,
// each owning 4 of the 8 q-components. Leave-one-out products factor as
// (local 3-product) x (partner 4-product); partner's {prod a, prod b,
// sum alpha, sum alpha^2} arrive via one shfl_xor(1) each. This halves
// per-thread registers (-> 8 waves/SIMD) and serial chain length.
// 32 lanes per token (16 heads x 2 halves); output projection partials are
// reduce-scattered over those 32 lanes (j-set halves on xor 1/2/4, plain
// sums on xor 8/16); the softmax reciprocal rl is folded into numer before
// the cross-head reduction.

static constexpr int HEADS = 16;
static constexpr int BN = 8 * 4096;  // tokens

__global__ __launch_bounds__(256) void e8_attn_kernel(
    const float* __restrict__ x,
    const float* __restrict__ wq,
    const float* __restrict__ bq,
    const float* __restrict__ wo,
    const float* __restrict__ bo,
    float* __restrict__ out)
{
    const int t = blockIdx.x * 256 + threadIdx.x;
    const int g = t & 1;          // component half: k in [4g, 4g+3]
    const int h = (t >> 1) & 15;  // head
    const int token = t >> 5;

    // ---- x[token] (all 32 lanes of a token hit the same 32B) ----
    const float4 x0 = *(const float4*)(x + token * 8);
    const float4 x1 = *(const float4*)(x + token * 8 + 4);
    const float xv[8] = {x0.x, x0.y, x0.z, x0.w, x1.x, x1.y, x1.z, x1.w};

    // ---- q for my 4 components ----
    const int col = h * 8 + g * 4;
    float q[4];
    {
        const float4 qb = *(const float4*)(bq + col);
        q[0] = qb.x; q[1] = qb.y; q[2] = qb.z; q[3] = qb.w;
#pragma unroll
        for (int i = 0; i < 8; ++i) {
            const float4 w = *(const float4*)(wq + i * 128 + col);
            q[0] = fmaf(xv[i], w.x, q[0]);
            q[1] = fmaf(xv[i], w.y, q[1]);
            q[2] = fmaf(xv[i], w.z, q[2]);
            q[3] = fmaf(xv[i], w.w, q[3]);
        }
    }

    // ---- hyperbolic blocks for my 4 components ----
    const float C2 = 0.25506807186927930f;  // log2(e) / (2 sqrt 8)
    float a[4], b[4];
    float SaL = 0.f, Sa2L = 0.f;
#pragma unroll
    for (int k = 0; k < 4; ++k) {
        const float w  = __builtin_exp2f(C2 * q[k]);
        const float iw = __builtin_amdgcn_rcpf(w);
        const float av = w + iw;
        const float bv = w - iw;
        a[k] = av; b[k] = bv;
        const float alpha = fmaf(av, av, -2.0f);
        SaL += alpha;
        Sa2L = fmaf(alpha, alpha, Sa2L);
    }

    // ---- local leave-one-out 3-products and full 4-products ----
    const float pa01 = a[0] * a[1], pa23 = a[2] * a[3];
    const float pb01 = b[0] * b[1], pb23 = b[2] * b[3];
    float loA[4], loB[4];
    loA[0] = a[1] * pa23; loA[1] = a[0] * pa23;
    loA[2] = pa01 * a[3]; loA[3] = pa01 * a[2];
    loB[0] = b[1] * pb23; loB[1] = b[0] * pb23;
    loB[2] = pb01 * b[3]; loB[3] = pb01 * b[2];
    const float PaL = pa01 * pa23;
    const float PbL = pb01 * pb23;

    // ---- exchange with partner lane (same token/head, other half) ----
    const float PaO  = __shfl_xor(PaL, 1, 64);
    const float PbO  = __shfl_xor(PbL, 1, 64);
    const float SaO  = __shfl_xor(SaL, 1, 64);
    const float Sa2O = __shfl_xor(Sa2L, 1, 64);

    const float Sa  = SaL + SaO;
    const float Sa2 = Sa2L + Sa2O;
    const float PA  = PaL * PaO;
    const float PB  = PbL * PbO;
    const float l   = 0.5f * (Sa * Sa - Sa2) + 0.5f * (PA + PB);
    const float rl  = __builtin_amdgcn_rcpf(l);

    // ---- numer (with rl folded) + output projection over my 4 rows ----
    float po[8] = {0.f,0.f,0.f,0.f,0.f,0.f,0.f,0.f};
    const float* wo_g = wo + col * 8;  // rows (h*8 + 4g + kk) of wo
#pragma unroll
    for (int k = 0; k < 4; ++k) {
        const float av = a[k], bv = b[k];
        const float alpha = fmaf(av, av, -2.0f);
        const float pair  = (av * bv) * (Sa - alpha);
        const float half  = 0.25f * fmaf(bv, loA[k] * PaO, av * (loB[k] * PbO));
        const float nm    = (pair + half) * rl;
        const float4 w0 = *(const float4*)(wo_g + k * 8);
        const float4 w1 = *(const float4*)(wo_g + k * 8 + 4);
        po[0] = fmaf(nm, w0.x, po[0]);
        po[1] = fmaf(nm, w0.y, po[1]);
        po[2] = fmaf(nm, w0.z, po[2]);
        po[3] = fmaf(nm, w0.w, po[3]);
        po[4] = fmaf(nm, w1.x, po[4]);
        po[5] = fmaf(nm, w1.y, po[5]);
        po[6] = fmaf(nm, w1.z, po[6]);
        po[7] = fmaf(nm, w1.w, po[7]);
    }

    // ---- reduce-scatter over the 32 lanes of this token ----
    const bool b0 = (t & 1) != 0;
    const bool b1 = (t & 2) != 0;
    const bool b2 = (t & 4) != 0;
    // xor 1: keep 4 components (upper half if b0)
    float r4[4];
#pragma unroll
    for (int m = 0; m < 4; ++m) {
        const float send = b0 ? po[m] : po[4 + m];
        const float keep = b0 ? po[4 + m] : po[m];
        r4[m] = keep + __shfl_xor(send, 1, 64);
    }
    // xor 2: keep 2
    float r2v[2];
#pragma unroll
    for (int m = 0; m < 2; ++m) {
        const float send = b1 ? r4[m] : r4[2 + m];
        const float keep = b1 ? r4[2 + m] : r4[m];
        r2v[m] = keep + __shfl_xor(send, 2, 64);
    }
    // xor 4: keep 1  (j = 4*b0 + 2*b1 + b2)
    float r1;
    {
        const float send = b2 ? r2v[0] : r2v[1];
        const float keep = b2 ? r2v[1] : r2v[0];
        r1 = keep + __shfl_xor(send, 4, 64);
    }
    // xor 8, xor 16: plain sums across replicas of the same j
    r1 += __shfl_xor(r1, 8, 64);
    r1 += __shfl_xor(r1, 16, 64);

    // one writer per (token, j): lanes with (t & 24) == 0
    if ((t & 24) == 0) {
        const int j = ((t & 1) << 2) | (t & 2) | ((t >> 2) & 1);
        out[token * 8 + j] = r1 + bo[j];
    }
}

extern "C" void kernel_launch(void* const* d_in, const int* in_sizes, int n_in,
                              void* d_out, int out_size, void* d_ws, size_t ws_size,
                              hipStream_t stream) {
    const float* x  = (const float*)d_in[0];
    const float* wq = (const float*)d_in[1];
    const float* bq = (const float*)d_in[2];
    // d_in[3..6] = wk, bk, wv, bv: dead code in the reference
    const float* wo = (const float*)d_in[7];
    const float* bo = (const float*)d_in[8];
    float* out = (float*)d_out;

    const int threads = BN * HEADS * 2;     // 1048576 -> 4096 blocks x 256
    e8_attn_kernel<<<threads / 256, 256, 0, stream>>>(x, wq, bq, wo, bo, out);
}

// Round 4
// 13.033 us; speedup vs baseline: 2.0044x; 2.0044x over previous
//
#include <hip/hip_runtime.h>

// E8 attention, closed-form softmax over the E8 root codebook.
//
// Per (token, head), q in R^8, s_r = (q.r)/sqrt(8), p = softmax(s),
// ctx = sum_r p_r r.  With c = 1/(2 sqrt 8), w = exp(c q_k), iw = 1/w:
//   a_k = w + iw (>= 2), b_k = w - iw, alpha_k = a_k^2 - 2, beta_k = a_k b_k,
//   T_k = tanh(c q_k) = b_k / a_k.
// Pair roots (112):  numer_i = beta_i (Sa - alpha_i) = (alpha_i+2) T_i (Sa - alpha_i),
//   denom_pair = 0.5 (Sa^2 - sum alpha^2),  Sa = sum alpha.
// Half roots (128, even parity), single-LOO-family form:
//   b_k prod_{m!=k} a_m + a_k prod_{m!=k} b_m = Pa (T_k + prod_{m!=k} T_m),
//   denom_half = 0.5 (Pa + Pb) = 0.5 Pa (1 + prod T),   Pa = prod a.
//   => numer_half_k = 0.25 Pa (T_k + preT_k * sufT_k)   (LOO over T only; no
//      division by b needed, and a_k >= 2 so T_k is always well-defined).
// Exact reformulation; |scores| ~ 1 so f32 exp cannot overflow.
//
// Layout: 16 lanes per token-group (one per head), T=4 tokens per thread so
// wq/bq/wo loads amortize 4x. 131072 threads = 2048 waves (fully resident).
// Both GEMM blocks use packed f32x2 fma (v_pk_fma_f32 on gfx950).
// Output projection partials reduce-scatter over the 16 head lanes
// (component set halves per xor-8/4/2 stage; lane h ends owning j = h>>1).

typedef float f32x2 __attribute__((ext_vector_type(2)));

static constexpr int HEADS = 16;
static constexpr int BN = 8 * 4096;  // tokens
static constexpr int T = 4;          // tokens per thread

__global__ __launch_bounds__(256) void e8_attn_kernel(
    const float* __restrict__ x,
    const float* __restrict__ wq,
    const float* __restrict__ bq,
    const float* __restrict__ wo,
    const float* __restrict__ bo,
    float* __restrict__ out)
{
    const int t = blockIdx.x * 256 + threadIdx.x;
    const int p = t >> 4;        // token-group index
    const int h = t & 15;        // head
    const int tok = p * T;
    const int col = h * 8;

    // ---- x for T tokens (contiguous 128 B per group, broadcast across heads)
    float4 xa[T], xb[T];
#pragma unroll
    for (int u = 0; u < T; ++u) {
        xa[u] = *(const float4*)(x + (tok + u) * 8);
        xb[u] = *(const float4*)(x + (tok + u) * 8 + 4);
    }

    // ---- q = x @ wq + bq for my head, packed pairs, wq amortized over T ----
    f32x2 q[T][4];
    {
        const float4 b0 = *(const float4*)(bq + col);
        const float4 b1 = *(const float4*)(bq + col + 4);
#pragma unroll
        for (int u = 0; u < T; ++u) {
            q[u][0] = (f32x2){b0.x, b0.y};
            q[u][1] = (f32x2){b0.z, b0.w};
            q[u][2] = (f32x2){b1.x, b1.y};
            q[u][3] = (f32x2){b1.z, b1.w};
        }
    }
#pragma unroll
    for (int i = 0; i < 8; ++i) {
        const float4 w0 = *(const float4*)(wq + i * 128 + col);
        const float4 w1 = *(const float4*)(wq + i * 128 + col + 4);
        const f32x2 wv0 = {w0.x, w0.y}, wv1 = {w0.z, w0.w};
        const f32x2 wv2 = {w1.x, w1.y}, wv3 = {w1.z, w1.w};
#pragma unroll
        for (int u = 0; u < T; ++u) {
            const float xi =
                (i == 0) ? xa[u].x : (i == 1) ? xa[u].y : (i == 2) ? xa[u].z :
                (i == 3) ? xa[u].w : (i == 4) ? xb[u].x : (i == 5) ? xb[u].y :
                (i == 6) ? xb[u].z : xb[u].w;
            const f32x2 xs = {xi, xi};
            q[u][0] = __builtin_elementwise_fma(xs, wv0, q[u][0]);
            q[u][1] = __builtin_elementwise_fma(xs, wv1, q[u][1]);
            q[u][2] = __builtin_elementwise_fma(xs, wv2, q[u][2]);
            q[u][3] = __builtin_elementwise_fma(xs, wv3, q[u][3]);
        }
    }

    // ---- hyperbolic blocks: alpha_k, T_k, Sa, Sa2, Pa per token ----
    const float C2 = 0.25506807186927930f;  // log2(e) / (2 sqrt 8)
    float alpha[T][8], Tt[T][8];
    float Sa[T], Sa2[T], Pa[T];
#pragma unroll
    for (int u = 0; u < T; ++u) {
        Sa[u] = 0.f; Sa2[u] = 0.f; Pa[u] = 1.f;
#pragma unroll
        for (int k = 0; k < 8; ++k) {
            const float qk = q[u][k >> 1][k & 1];
            const float w  = __builtin_exp2f(C2 * qk);
            const float iw = __builtin_amdgcn_rcpf(w);
            const float av = w + iw;
            const float bv = w - iw;
            const float tk = bv * __builtin_amdgcn_rcpf(av);
            const float al = fmaf(av, av, -2.0f);
            alpha[u][k] = al; Tt[u][k] = tk;
            Sa[u] += al;
            Sa2[u] = fmaf(al, al, Sa2[u]);
            Pa[u] *= av;
        }
    }

    // ---- suffix products of T; denominator; fold reciprocal ----
    float sufT[T][8], rl[T], qPa[T];
#pragma unroll
    for (int u = 0; u < T; ++u) {
        sufT[u][7] = 1.f;
#pragma unroll
        for (int k = 6; k >= 0; --k) sufT[u][k] = sufT[u][k + 1] * Tt[u][k + 1];
        const float PT = sufT[u][0] * Tt[u][0];
        const float l  = 0.5f * (Sa[u] * Sa[u] - Sa2[u])
                       + 0.5f * Pa[u] * (1.f + PT);
        rl[u]  = __builtin_amdgcn_rcpf(l);
        qPa[u] = 0.25f * Pa[u] * rl[u];
    }

    // ---- fused numer + output projection (wo amortized over T) ----
    f32x2 po[T][4];
#pragma unroll
    for (int u = 0; u < T; ++u)
#pragma unroll
        for (int m = 0; m < 4; ++m) po[u][m] = (f32x2){0.f, 0.f};

    float preT[T];
#pragma unroll
    for (int u = 0; u < T; ++u) preT[u] = 1.f;

    const float* wo_h = wo + col * 8;
#pragma unroll
    for (int k = 0; k < 8; ++k) {
        const float4 w0 = *(const float4*)(wo_h + k * 8);
        const float4 w1 = *(const float4*)(wo_h + k * 8 + 4);
        const f32x2 wv0 = {w0.x, w0.y}, wv1 = {w0.z, w0.w};
        const f32x2 wv2 = {w1.x, w1.y}, wv3 = {w1.z, w1.w};
#pragma unroll
        for (int u = 0; u < T; ++u) {
            const float al = alpha[u][k], tk = Tt[u][k];
            const float pair = ((al + 2.0f) * tk) * (Sa[u] - al);
            const float loo  = preT[u] * sufT[u][k];
            const float nm   = fmaf(pair, rl[u], qPa[u] * (tk + loo));
            preT[u] *= tk;
            const f32x2 ns = {nm, nm};
            po[u][0] = __builtin_elementwise_fma(ns, wv0, po[u][0]);
            po[u][1] = __builtin_elementwise_fma(ns, wv1, po[u][1]);
            po[u][2] = __builtin_elementwise_fma(ns, wv2, po[u][2]);
            po[u][3] = __builtin_elementwise_fma(ns, wv3, po[u][3]);
        }
    }

    // ---- reduce-scatter over the 16 head lanes (r2-verified mapping) ----
    const bool h3 = (h & 8) != 0;
    const bool h2 = (h & 4) != 0;
    const bool h1 = (h & 2) != 0;
    float rr[T];
#pragma unroll
    for (int u = 0; u < T; ++u) {
        float po8[8];
#pragma unroll
        for (int j = 0; j < 8; ++j) po8[j] = po[u][j >> 1][j & 1];
        float r4[4];
#pragma unroll
        for (int m = 0; m < 4; ++m) {
            const float send = h3 ? po8[m] : po8[4 + m];
            const float keep = h3 ? po8[4 + m] : po8[m];
            r4[m] = keep + __shfl_xor(send, 8, 64);
        }
        float r2v[2];
#pragma unroll
        for (int m = 0; m < 2; ++m) {
            const float send = h2 ? r4[m] : r4[2 + m];
            const float keep = h2 ? r4[2 + m] : r4[m];
            r2v[m] = keep + __shfl_xor(send, 4, 64);
        }
        {
            const float send = h1 ? r2v[0] : r2v[1];
            const float keep = h1 ? r2v[1] : r2v[0];
            rr[u] = keep + __shfl_xor(send, 2, 64);
        }
        rr[u] += __shfl_xor(rr[u], 1, 64);
    }

    // lane h (h even) owns output component j = h>>1 for its T tokens
    if ((h & 1) == 0) {
        const int j = h >> 1;
        const float boj = bo[j];
#pragma unroll
        for (int u = 0; u < T; ++u)
            out[(tok + u) * 8 + j] = rr[u] + boj;
    }
}

extern "C" void kernel_launch(void* const* d_in, const int* in_sizes, int n_in,
                              void* d_out, int out_size, void* d_ws, size_t ws_size,
                              hipStream_t stream) {
    const float* x  = (const float*)d_in[0];
    const float* wq = (const float*)d_in[1];
    const float* bq = (const float*)d_in[2];
    // d_in[3..6] = wk, bk, wv, bv: dead code in the reference
    const float* wo = (const float*)d_in[7];
    const float* bo = (const float*)d_in[8];
    float* out = (float*)d_out;

    const int threads = (BN / T) * HEADS;   // 131072 -> 512 blocks x 256
    e8_attn_kernel<<<threads / 256, 256, 0, stream>>>(x, wq, bq, wo, bo, out);
}

// Round 5
// 11.928 us; speedup vs baseline: 2.1900x; 1.0926x over previous
//
#include <hip/hip_runtime.h>

// E8 attention, closed-form softmax over the E8 root codebook.
//
// Per (token, head), q in R^8, s_r = (q.r)/sqrt(8), p = softmax(s),
// ctx = sum_r p_r r.  W-form: W_k = exp(q_k/sqrt8),
//   alpha_k = W + 1/W  (= 2cosh(q/sqrt8))
//   beta_k  = W - 1/W  (= 2sinh(q/sqrt8))
//   t_k     = beta/(alpha+2) = (W-1)/(W+1) = tanh(q/(2 sqrt8))
//   a_k^2   = alpha+2  =>  Pa = prod a_k = sqrt(prod(alpha_k+2))
// Pair roots (112): numer_i = beta_i (Sa - alpha_i),
//   denom_pair = 0.5 (Sa^2 - sum alpha^2),  Sa = sum alpha.
// Half roots (128, even parity): denom_half = 0.5 Pa (1 + prod t),
//   numer_k = 0.25 Pa (t_k + prod_{m!=k} t_m)   (LOO over t via suffix prods).
// Exact reformulation; |q| small so f32 exp/sqrt/rcp are all safe.
//
// Layout: 16 lanes per token-group (one per head), T=4 tokens per thread.
// Token PAIRS are packed into f32x2 so hyper/suffix/denom/numer arithmetic
// runs on v_pk_*_f32 (2 tokens per instruction); exp/rcp/sqrt stay scalar.
// Output projection partials reduce-scatter over the 16 head lanes
// (r2-verified mapping; lane h ends owning component j = h>>1).

typedef float f32x2 __attribute__((ext_vector_type(2)));

static constexpr int HEADS = 16;
static constexpr int BN = 8 * 4096;  // tokens
static constexpr int T = 4;          // tokens per thread
static constexpr int P = 2;          // token pairs per thread

__global__ __launch_bounds__(256) void e8_attn_kernel(
    const float* __restrict__ x,
    const float* __restrict__ wq,
    const float* __restrict__ bq,
    const float* __restrict__ wo,
    const float* __restrict__ bo,
    float* __restrict__ out)
{
    const int t = blockIdx.x * 256 + threadIdx.x;
    const int h = t & 15;         // head
    const int tok = (t >> 4) * T; // first token of this thread's group
    const int col = h * 8;

    // ---- x packed across token pairs: xp[pp][i] = {x[2pp][i], x[2pp+1][i]}
    f32x2 xp[P][8];
#pragma unroll
    for (int pp = 0; pp < P; ++pp) {
        const float4 a0 = *(const float4*)(x + (tok + 2 * pp) * 8);
        const float4 b0 = *(const float4*)(x + (tok + 2 * pp) * 8 + 4);
        const float4 a1 = *(const float4*)(x + (tok + 2 * pp + 1) * 8);
        const float4 b1 = *(const float4*)(x + (tok + 2 * pp + 1) * 8 + 4);
        xp[pp][0] = (f32x2){a0.x, a1.x};
        xp[pp][1] = (f32x2){a0.y, a1.y};
        xp[pp][2] = (f32x2){a0.z, a1.z};
        xp[pp][3] = (f32x2){a0.w, a1.w};
        xp[pp][4] = (f32x2){b0.x, b1.x};
        xp[pp][5] = (f32x2){b0.y, b1.y};
        xp[pp][6] = (f32x2){b0.z, b1.z};
        xp[pp][7] = (f32x2){b0.w, b1.w};
    }

    // ---- q = x @ wq + bq for my head, token-pair packed ----
    f32x2 q[P][8];
    {
        const float4 c0 = *(const float4*)(bq + col);
        const float4 c1 = *(const float4*)(bq + col + 4);
        const float bqs[8] = {c0.x, c0.y, c0.z, c0.w, c1.x, c1.y, c1.z, c1.w};
#pragma unroll
        for (int k = 0; k < 8; ++k) {
            const f32x2 bb = {bqs[k], bqs[k]};
#pragma unroll
            for (int pp = 0; pp < P; ++pp) q[pp][k] = bb;
        }
    }
#pragma unroll
    for (int i = 0; i < 8; ++i) {
        const float4 w0 = *(const float4*)(wq + i * 128 + col);
        const float4 w1 = *(const float4*)(wq + i * 128 + col + 4);
        const float ws[8] = {w0.x, w0.y, w0.z, w0.w, w1.x, w1.y, w1.z, w1.w};
#pragma unroll
        for (int k = 0; k < 8; ++k) {
            const f32x2 wv = {ws[k], ws[k]};
#pragma unroll
            for (int pp = 0; pp < P; ++pp)
                q[pp][k] = __builtin_elementwise_fma(xp[pp][i], wv, q[pp][k]);
        }
    }

    // ---- scale so W = exp2(q') = exp(q/sqrt8) ----
    const float CW = 0.51006973f;  // log2(e)/sqrt(8)
#pragma unroll
    for (int k = 0; k < 8; ++k)
#pragma unroll
        for (int pp = 0; pp < P; ++pp) q[pp][k] = q[pp][k] * CW;

    // ---- hyperbolic blocks (token-pair packed) ----
    f32x2 Sm[P][8], beta[P][8], tkv[P][8];
    f32x2 Sa[P], Sa2[P], P2[P];
#pragma unroll
    for (int pp = 0; pp < P; ++pp) {
        Sa[pp]  = (f32x2){0.f, 0.f};
        Sa2[pp] = (f32x2){0.f, 0.f};
        P2[pp]  = (f32x2){1.f, 1.f};
    }
#pragma unroll
    for (int k = 0; k < 8; ++k) {
#pragma unroll
        for (int pp = 0; pp < P; ++pp) {
            f32x2 W, iW, rd;
            W.x  = __builtin_amdgcn_exp2f(q[pp][k].x);
            W.y  = __builtin_amdgcn_exp2f(q[pp][k].y);
            iW.x = __builtin_amdgcn_rcpf(W.x);
            iW.y = __builtin_amdgcn_rcpf(W.y);
            const f32x2 al = W + iW;
            const f32x2 be = W - iW;
            const f32x2 d  = al + 2.0f;
            rd.x = __builtin_amdgcn_rcpf(d.x);
            rd.y = __builtin_amdgcn_rcpf(d.y);
            beta[pp][k] = be;
            tkv[pp][k]  = be * rd;
            Sm[pp][k]   = al;  // alpha for now; becomes Sa - alpha below
            Sa[pp]  = Sa[pp] + al;
            Sa2[pp] = __builtin_elementwise_fma(al, al, Sa2[pp]);
            P2[pp]  = P2[pp] * d;
        }
    }
#pragma unroll
    for (int k = 0; k < 8; ++k)
#pragma unroll
        for (int pp = 0; pp < P; ++pp) Sm[pp][k] = Sa[pp] - Sm[pp][k];

    // ---- suffix products of t; denominator; fold reciprocal ----
    f32x2 sufT[P][8], rl[P], qPa[P];
#pragma unroll
    for (int pp = 0; pp < P; ++pp) {
        sufT[pp][7] = (f32x2){1.f, 1.f};
#pragma unroll
        for (int k = 6; k >= 0; --k)
            sufT[pp][k] = sufT[pp][k + 1] * tkv[pp][k + 1];
        const f32x2 PT = sufT[pp][0] * tkv[pp][0];
        f32x2 Pa;
        Pa.x = __builtin_amdgcn_sqrtf(P2[pp].x);
        Pa.y = __builtin_amdgcn_sqrtf(P2[pp].y);
        const f32x2 l = 0.5f * __builtin_elementwise_fma(Sa[pp], Sa[pp], -Sa2[pp])
                      + (0.5f * Pa) * (PT + 1.0f);
        f32x2 r;
        r.x = __builtin_amdgcn_rcpf(l.x);
        r.y = __builtin_amdgcn_rcpf(l.y);
        rl[pp]  = r;
        qPa[pp] = (0.25f * Pa) * r;
    }

    // ---- fused numer + output projection ----
    f32x2 po[T][4];
#pragma unroll
    for (int u = 0; u < T; ++u)
#pragma unroll
        for (int m = 0; m < 4; ++m) po[u][m] = (f32x2){0.f, 0.f};

    f32x2 preT[P];
#pragma unroll
    for (int pp = 0; pp < P; ++pp) preT[pp] = (f32x2){1.f, 1.f};

    const float* wo_h = wo + col * 8;
#pragma unroll
    for (int k = 0; k < 8; ++k) {
        const float4 w0 = *(const float4*)(wo_h + k * 8);
        const float4 w1 = *(const float4*)(wo_h + k * 8 + 4);
        const f32x2 wv0 = {w0.x, w0.y}, wv1 = {w0.z, w0.w};
        const f32x2 wv2 = {w1.x, w1.y}, wv3 = {w1.z, w1.w};
#pragma unroll
        for (int pp = 0; pp < P; ++pp) {
            const f32x2 pairnm = beta[pp][k] * Sm[pp][k];
            const f32x2 loo    = preT[pp] * sufT[pp][k];
            const f32x2 tkl    = tkv[pp][k] + loo;
            const f32x2 nm     = __builtin_elementwise_fma(pairnm, rl[pp], qPa[pp] * tkl);
            preT[pp] = preT[pp] * tkv[pp][k];
            const f32x2 n0 = {nm.x, nm.x};
            const f32x2 n1 = {nm.y, nm.y};
            po[2*pp][0]   = __builtin_elementwise_fma(n0, wv0, po[2*pp][0]);
            po[2*pp][1]   = __builtin_elementwise_fma(n0, wv1, po[2*pp][1]);
            po[2*pp][2]   = __builtin_elementwise_fma(n0, wv2, po[2*pp][2]);
            po[2*pp][3]   = __builtin_elementwise_fma(n0, wv3, po[2*pp][3]);
            po[2*pp+1][0] = __builtin_elementwise_fma(n1, wv0, po[2*pp+1][0]);
            po[2*pp+1][1] = __builtin_elementwise_fma(n1, wv1, po[2*pp+1][1]);
            po[2*pp+1][2] = __builtin_elementwise_fma(n1, wv2, po[2*pp+1][2]);
            po[2*pp+1][3] = __builtin_elementwise_fma(n1, wv3, po[2*pp+1][3]);
        }
    }

    // ---- reduce-scatter over the 16 head lanes (r2-verified mapping) ----
    const bool h3 = (h & 8) != 0;
    const bool h2 = (h & 4) != 0;
    const bool h1 = (h & 2) != 0;
    float rr[T];
#pragma unroll
    for (int u = 0; u < T; ++u) {
        float po8[8];
#pragma unroll
        for (int j = 0; j < 8; ++j) po8[j] = po[u][j >> 1][j & 1];
        float r4[4];
#pragma unroll
        for (int m = 0; m < 4; ++m) {
            const float send = h3 ? po8[m] : po8[4 + m];
            const float keep = h3 ? po8[4 + m] : po8[m];
            r4[m] = keep + __shfl_xor(send, 8, 64);
        }
        float r2v[2];
#pragma unroll
        for (int m = 0; m < 2; ++m) {
            const float send = h2 ? r4[m] : r4[2 + m];
            const float keep = h2 ? r4[2 + m] : r4[m];
            r2v[m] = keep + __shfl_xor(send, 4, 64);
        }
        {
            const float send = h1 ? r2v[0] : r2v[1];
            const float keep = h1 ? r2v[1] : r2v[0];
            rr[u] = keep + __shfl_xor(send, 2, 64);
        }
        rr[u] += __shfl_xor(rr[u], 1, 64);
    }

    // lane h (h even) owns output component j = h>>1 for its T tokens
    if ((h & 1) == 0) {
        const int j = h >> 1;
        const float boj = bo[j];
#pragma unroll
        for (int u = 0; u < T; ++u)
            out[(tok + u) * 8 + j] = rr[u] + boj;
    }
}

extern "C" void kernel_launch(void* const* d_in, const int* in_sizes, int n_in,
                              void* d_out, int out_size, void* d_ws, size_t ws_size,
                              hipStream_t stream) {
    const float* x  = (const float*)d_in[0];
    const float* wq = (const float*)d_in[1];
    const float* bq = (const float*)d_in[2];
    // d_in[3..6] = wk, bk, wv, bv: dead code in the reference
    const float* wo = (const float*)d_in[7];
    const float* bo = (const float*)d_in[8];
    float* out = (float*)d_out;

    const int threads = (BN / T) * HEADS;   // 131072 -> 512 blocks x 256
    e8_attn_kernel<<<threads / 256, 256, 0, stream>>>(x, wq, bq, wo, bo, out);
}